// Round 1
// baseline (32.674 us; speedup 1.0000x reference)
//
#include <hip/hip_runtime.h>
#include <math.h>

// Loss_58317065945194: per-sample EMD over C=10 bins, averaged over B samples.
//   diff = p - q               [B, C]
//   cdf  = cumsum(diff, axis=1)
//   per_sample = (mean_c |cdf|^r)^(1/r)
//   out = mean_b per_sample
// Memory-bound: 2 * B*C*4 bytes read, 4 bytes written.

constexpr int C = 10;
constexpr int BLOCK = 256;

__device__ __forceinline__ float block_reduce_sum(float v) {
    // wave(64) shuffle reduce, then LDS across the 4 waves of a 256 block
    #pragma unroll
    for (int off = 32; off > 0; off >>= 1)
        v += __shfl_down(v, off, 64);
    __shared__ float smem[BLOCK / 64];
    const int lane = threadIdx.x & 63;
    const int wid  = threadIdx.x >> 6;
    if (lane == 0) smem[wid] = v;
    __syncthreads();
    float s = 0.0f;
    if (threadIdx.x == 0) {
        #pragma unroll
        for (int w = 0; w < BLOCK / 64; ++w) s += smem[w];
    }
    return s;  // valid in thread 0 only
}

__global__ __launch_bounds__(BLOCK) void emd_partial(
    const float* __restrict__ p, const float* __restrict__ q,
    const int* __restrict__ rptr, float* __restrict__ partial, int B)
{
    const int tid = blockIdx.x * blockDim.x + threadIdx.x;
    const int nth = gridDim.x * blockDim.x;
    const int r   = rptr[0];
    const int npairs = B >> 1;

    float local = 0.0f;

    if (r == 2) {
        for (int pi = tid; pi < npairs; pi += nth) {
            // 2 samples = 20 floats = 5 float4 per array; byte base pi*80 is 16B-aligned
            const float4* p4 = reinterpret_cast<const float4*>(p) + (size_t)pi * 5;
            const float4* q4 = reinterpret_cast<const float4*>(q) + (size_t)pi * 5;
            float d[2 * C];
            #pragma unroll
            for (int k = 0; k < 5; ++k) {
                float4 a = p4[k];
                float4 b = q4[k];
                d[4*k+0] = a.x - b.x;
                d[4*k+1] = a.y - b.y;
                d[4*k+2] = a.z - b.z;
                d[4*k+3] = a.w - b.w;
            }
            #pragma unroll
            for (int s = 0; s < 2; ++s) {
                float cum = 0.0f, acc = 0.0f;
                #pragma unroll
                for (int c = 0; c < C; ++c) {
                    cum += d[s * C + c];
                    acc += cum * cum;
                }
                local += sqrtf(acc * (1.0f / C));
            }
        }
    } else {
        const float rf = (float)r;
        const float rinv = 1.0f / rf;
        for (int pi = tid; pi < npairs; pi += nth) {
            const float4* p4 = reinterpret_cast<const float4*>(p) + (size_t)pi * 5;
            const float4* q4 = reinterpret_cast<const float4*>(q) + (size_t)pi * 5;
            float d[2 * C];
            #pragma unroll
            for (int k = 0; k < 5; ++k) {
                float4 a = p4[k];
                float4 b = q4[k];
                d[4*k+0] = a.x - b.x;
                d[4*k+1] = a.y - b.y;
                d[4*k+2] = a.z - b.z;
                d[4*k+3] = a.w - b.w;
            }
            #pragma unroll
            for (int s = 0; s < 2; ++s) {
                float cum = 0.0f, acc = 0.0f;
                #pragma unroll
                for (int c = 0; c < C; ++c) {
                    cum += d[s * C + c];
                    acc += powf(fabsf(cum), rf);
                }
                local += powf(acc * (1.0f / C), rinv);
            }
        }
    }

    // tail sample if B is odd (not expected for B=2M, but be correct)
    if ((B & 1) && tid == 0) {
        const size_t base = (size_t)(B - 1) * C;
        float cum = 0.0f, acc = 0.0f;
        for (int c = 0; c < C; ++c) {
            cum += p[base + c] - q[base + c];
            acc += (r == 2) ? cum * cum : powf(fabsf(cum), (float)r);
        }
        local += (r == 2) ? sqrtf(acc * (1.0f / C))
                          : powf(acc * (1.0f / C), 1.0f / (float)r);
    }

    float s = block_reduce_sum(local);
    if (threadIdx.x == 0) partial[blockIdx.x] = s;
}

__global__ __launch_bounds__(BLOCK) void emd_reduce(
    const float* __restrict__ partial, int n, float* __restrict__ out, float invB)
{
    float local = 0.0f;
    for (int i = threadIdx.x; i < n; i += BLOCK) local += partial[i];
    float s = block_reduce_sum(local);
    if (threadIdx.x == 0) out[0] = s * invB;
}

extern "C" void kernel_launch(void* const* d_in, const int* in_sizes, int n_in,
                              void* d_out, int out_size, void* d_ws, size_t ws_size,
                              hipStream_t stream) {
    const float* p = (const float*)d_in[0];
    const float* q = (const float*)d_in[1];
    const int*   r = (const int*)d_in[2];
    float* out     = (float*)d_out;
    float* partial = (float*)d_ws;

    const int B = in_sizes[0] / C;

    int nblocks = 2048;  // 256 CUs * 8 blocks/CU; grid-stride covers the rest
    const int max_ws_blocks = (int)(ws_size / sizeof(float));
    if (nblocks > max_ws_blocks) nblocks = max_ws_blocks;
    if (nblocks < 1) nblocks = 1;

    emd_partial<<<nblocks, BLOCK, 0, stream>>>(p, q, r, partial, B);
    emd_reduce<<<1, BLOCK, 0, stream>>>(partial, nblocks, out, 1.0f / (float)B);
}